// Round 2
// baseline (914.729 us; speedup 1.0000x reference)
//
#include <hip/hip_runtime.h>
#include <hip/hip_bf16.h>
#include <stdint.h>

#define B_  2048
#define T_  16
#define F_  768
#define H_  1024
#define G4_ 4096   // 4*H

typedef __attribute__((ext_vector_type(8))) __bf16 bf16x8;
typedef __attribute__((ext_vector_type(4))) float  f32x4;

static __device__ __forceinline__ unsigned short f2bf(float f) {
    union { float f; uint32_t u; } v; v.f = f;
    uint32_t u = v.u;
    uint32_t r = (u + 0x7fffu + ((u >> 16) & 1u)) >> 16;   // RNE
    return (unsigned short)r;
}

static __device__ __forceinline__ float sigf(float x) {
    return 1.0f / (1.0f + __expf(-x));
}
static __device__ __forceinline__ float tanhfast(float x) {
    return 2.0f / (1.0f + __expf(-2.0f * x)) - 1.0f;
}

#define GLOAD_LDS16(gsrc, ldst)                                                       \
    __builtin_amdgcn_global_load_lds((const __attribute__((address_space(1))) void*)(gsrc), \
                                     (__attribute__((address_space(3))) void*)(ldst), \
                                     16, 0, 0)

// ---------------------------------------------------------------- prep kernels

__global__ void convert_x_kernel(const float* __restrict__ x,
                                 unsigned short* __restrict__ xbf, int n4) {
    int idx = blockIdx.x * blockDim.x + threadIdx.x;
    if (idx >= n4) return;
    float4 v = *(const float4*)(x + (size_t)idx * 4);
    ushort4 o;
    o.x = f2bf(v.x); o.y = f2bf(v.y); o.z = f2bf(v.z); o.w = f2bf(v.w);
    *(ushort4*)(xbf + (size_t)idx * 4) = o;
}

// W [K][4096] f32  ->  Wt_perm [4096][K] bf16, gate-interleaved column order:
// original col n = gate*1024 + j  (j = hidden unit)
// new row  n' = (j>>5)*128 + ((j>>4)&1)*64 + gate*16 + (j&15)
// so a 128-row slice of Wt holds 32 complete units: [b(2)][gate(4)][u16(16)].
__global__ void transpose_w_kernel(const float* __restrict__ w,
                                   unsigned short* __restrict__ wt, int K) {
    __shared__ float tile[32][33];
    int nb = blockIdx.x * 32;   // over 4096 (original cols)
    int kb = blockIdx.y * 32;   // over K
    int tx = threadIdx.x, ty = threadIdx.y;
    #pragma unroll
    for (int i = 0; i < 32; i += 8)
        tile[ty + i][tx] = w[(size_t)(kb + ty + i) * G4_ + nb + tx];
    __syncthreads();
    #pragma unroll
    for (int i = 0; i < 32; i += 8) {
        int n = nb + ty + i;
        int g = n >> 10;
        int j = n & 1023;
        int np = (j >> 5) * 128 + ((j >> 4) & 1) * 64 + g * 16 + (j & 15);
        wt[(size_t)np * K + kb + tx] = f2bf(tile[tx][ty + i]);
    }
}

// ---------------------------------------------------------------- fused step
// gates = [x_t | h_prev] @ [Wih; Whh] (gate-interleaved cols) + bias,
// then LSTM cell fused in the epilogue.
// 128x128 tile, BK=32, 4 waves (2x2), each wave 64x64 via 4x4 frags of 16x16x32.

__global__ __launch_bounds__(256) void lstm_step_kernel(
        const unsigned short* __restrict__ xbf,    // [B][T][F] bf16
        const unsigned short* __restrict__ hprev,  // [B][H]    bf16 (read, t>0)
        const unsigned short* __restrict__ wih_t,  // [4096][768]  bf16 perm
        const unsigned short* __restrict__ whh_t,  // [4096][1024] bf16 perm
        const float* __restrict__ bias,            // [4096] original order
        float* __restrict__ c,                     // [B][H] f32 (r/w)
        unsigned short* __restrict__ hnext,        // [B][H] bf16 (write)
        float* __restrict__ hout,                  // [B][H] f32 (write if last)
        int t, int nkt, int first, int last) {
    __shared__ unsigned short lds_a[128 * 32];
    __shared__ unsigned short lds_b[128 * 32];

    const int tid  = threadIdx.x;
    const int wave = tid >> 6;
    const int lane = tid & 63;
    const int wr = wave >> 1, wc = wave & 1;
    const int bm0 = blockIdx.x * 128;
    const int bn0 = blockIdx.y * 128;

    f32x4 acc[4][4] = {};

    const int lr  = lane >> 2;          // 0..15: row within a 16-row staging group
    const int lk8 = (lane & 3) * 8;     // 0,8,16,24: bf16 elem offset within row

    const int fr = lane & 15;           // frag row/col index
    const int fk = (lane >> 4) * 8;     // frag k offset (0/8/16/24)

    for (int kt = 0; kt < nkt; ++kt) {  // 24 tiles from x (K=768), +32 from h (K=1024)
        const int k0 = kt * 32;
        const int r0 = wave * 32;
        // ---- stage A tile rows [r0, r0+32)
        #pragma unroll
        for (int half = 0; half < 2; ++half) {
            int row = r0 + half * 16 + lr;
            const unsigned short* src;
            if (k0 < F_)
                src = xbf + ((size_t)(bm0 + row) * (T_ * F_) + (size_t)t * F_ + k0 + lk8);
            else
                src = hprev + ((size_t)(bm0 + row) * H_ + (k0 - F_) + lk8);
            GLOAD_LDS16(src, lds_a + (size_t)(r0 + half * 16) * 32);
        }
        // ---- stage B tile cols [r0, r0+32)
        #pragma unroll
        for (int half = 0; half < 2; ++half) {
            int col = r0 + half * 16 + lr;
            const unsigned short* src;
            if (k0 < F_)
                src = wih_t + ((size_t)(bn0 + col) * F_ + k0 + lk8);
            else
                src = whh_t + ((size_t)(bn0 + col) * H_ + (k0 - F_) + lk8);
            GLOAD_LDS16(src, lds_b + (size_t)(r0 + half * 16) * 32);
        }
        __syncthreads();

        bf16x8 a_frag[4], b_frag[4];
        #pragma unroll
        for (int mi = 0; mi < 4; ++mi) {
            int row = wr * 64 + mi * 16 + fr;
            a_frag[mi] = *(const bf16x8*)(lds_a + row * 32 + fk);
        }
        #pragma unroll
        for (int ni = 0; ni < 4; ++ni) {
            int col = wc * 64 + ni * 16 + fr;
            b_frag[ni] = *(const bf16x8*)(lds_b + col * 32 + fk);
        }
        #pragma unroll
        for (int mi = 0; mi < 4; ++mi)
            #pragma unroll
            for (int ni = 0; ni < 4; ++ni)
                acc[mi][ni] = __builtin_amdgcn_mfma_f32_16x16x32_bf16(
                    a_frag[mi], b_frag[ni], acc[mi][ni], 0, 0, 0);
        __syncthreads();
    }

    // ---- fused LSTM-cell epilogue
    // col layout within tile: [wc=u_half][ni=gate][fr=u16]; this thread's unit:
    const int j = blockIdx.y * 32 + wc * 16 + fr;   // hidden unit index
    const float b_i = bias[j];
    const float b_f = bias[H_ + j];
    const float b_g = bias[2 * H_ + j];
    const float b_o = bias[3 * H_ + j];
    const int fq = lane >> 4;

    #pragma unroll
    for (int mi = 0; mi < 4; ++mi) {
        #pragma unroll
        for (int r = 0; r < 4; ++r) {
            int row = bm0 + wr * 64 + mi * 16 + fq * 4 + r;
            size_t off = (size_t)row * H_ + j;
            float gi = acc[mi][0][r] + b_i;
            float gf = acc[mi][1][r] + b_f;
            float gg = acc[mi][2][r] + b_g;
            float go = acc[mi][3][r] + b_o;
            float cold = first ? 0.0f : c[off];
            float cn = sigf(gf) * cold + sigf(gi) * tanhfast(gg);
            float hv = sigf(go) * tanhfast(cn);
            c[off] = cn;
            hnext[off] = f2bf(hv);
            if (last) hout[off] = hv;
        }
    }
}

// ---------------------------------------------------------------- launch

extern "C" void kernel_launch(void* const* d_in, const int* in_sizes, int n_in,
                              void* d_out, int out_size, void* d_ws, size_t ws_size,
                              hipStream_t stream) {
    const float* x    = (const float*)d_in[0];   // [B,T,F]
    const float* Wih  = (const float*)d_in[1];   // [F,4H]
    const float* Whh  = (const float*)d_in[2];   // [H,4H]
    const float* bias = (const float*)d_in[3];   // [4H]
    float* out = (float*)d_out;                  // [B,H] flat

    char* ws = (char*)d_ws;
    // ws layout (bytes)
    unsigned short* xbf   = (unsigned short*)(ws);                    // 50,331,648
    unsigned short* wih_t = (unsigned short*)(ws + 50331648);         //  6,291,456
    unsigned short* whh_t = (unsigned short*)(ws + 56623104);         //  8,388,608
    unsigned short* hbf0  = (unsigned short*)(ws + 65011712);         //  4,194,304
    unsigned short* hbf1  = (unsigned short*)(ws + 69206016);         //  4,194,304
    float*          c     = (float*)(ws + 73400320);                  //  8,388,608
    // total: 81,788,928 bytes

    // prep
    int n4 = B_ * T_ * F_ / 4;
    hipLaunchKernelGGL(convert_x_kernel, dim3((n4 + 255) / 256), dim3(256), 0, stream,
                       x, xbf, n4);
    hipLaunchKernelGGL(transpose_w_kernel, dim3(G4_ / 32, F_ / 32), dim3(32, 8), 0, stream,
                       Wih, wih_t, F_);
    hipLaunchKernelGGL(transpose_w_kernel, dim3(G4_ / 32, H_ / 32), dim3(32, 8), 0, stream,
                       Whh, whh_t, H_);

    // recurrence (h double-buffered; c owned per (row,unit) so no race;
    // t=0 reads neither h nor c: nkt=24 covers only the x phase, first=1)
    for (int t = 0; t < T_; ++t) {
        unsigned short* hr = (t & 1) ? hbf0 : hbf1;   // read (prev step's write)
        unsigned short* hw = (t & 1) ? hbf1 : hbf0;   // write
        int nkt   = (t == 0) ? 24 : 56;
        int first = (t == 0) ? 1 : 0;
        int last  = (t == T_ - 1) ? 1 : 0;
        hipLaunchKernelGGL(lstm_step_kernel, dim3(B_ / 128, G4_ / 128), dim3(256), 0, stream,
                           xbf, hr, wih_t, whh_t, bias, c, hw, out, t, nkt, first, last);
    }
}